// Round 7
// baseline (235.527 us; speedup 1.0000x reference)
//
#include <hip/hip_runtime.h>

#define HID 128
#define NNODE 10000
#define KN 16
#define ROWS 80000    // BATCH * NNODE
#define NTILES 2500   // ROWS / 32
#define ANCH 313      // ceil(NNODE/32) aggr row-chunks

typedef __attribute__((ext_vector_type(8))) short short8;   // 8 bf16 (4 VGPRs)
typedef __attribute__((ext_vector_type(4))) float f32x4;
typedef __attribute__((ext_vector_type(2))) float f32x2;
typedef __attribute__((ext_vector_type(2))) unsigned int u32x2;

__device__ __forceinline__ unsigned short f2b(float f) {
    unsigned u = __float_as_uint(f);
    u += 0x7FFFu + ((u >> 16) & 1u);       // round-to-nearest-even
    return (unsigned short)(u >> 16);
}

// All four weight transposes+converts in one launch.
__global__ __launch_bounds__(256) void wconv_all(
    const float* __restrict__ W1, const float* __restrict__ W2,
    const float* __restrict__ Wu1, const float* __restrict__ Wu2,
    unsigned short* __restrict__ W1t, unsigned short* __restrict__ W2t,
    unsigned short* __restrict__ Wu1t, unsigned short* __restrict__ Wu2t) {
    int idx = blockIdx.x * 256 + threadIdx.x;   // < 90112
    const float* W; unsigned short* Wt; int K; int off;
    if (idx < 8192)       { W = W1;  Wt = W1t;  K = 64;  off = idx; }
    else if (idx < 24576) { W = W2;  Wt = W2t;  K = 128; off = idx - 8192; }
    else if (idx < 57344) { W = Wu1; Wt = Wu1t; K = 256; off = idx - 24576; }
    else                  { W = Wu2; Wt = Wu2t; K = 256; off = idx - 57344; }
    int n = off & 127, k = off >> 7;
    Wt[n * K + k] = f2b(W[off]);
}

// Embed: Y[r][:] = relu(X[r][:] @ W + b), transposed-operand MFMA.
// 8 waves: rs = w&1 (16-row half of a 32-row tile), ng = w>>1 (32-col group).
// W-frags persistent in VGPRs; grid-stride; 2-deep x pipeline.
template<int K, bool AF32>
__global__ __launch_bounds__(512) void embed2(
    const void* __restrict__ A0, const void* __restrict__ A1,
    const unsigned short* __restrict__ Wt, const float* __restrict__ bias,
    unsigned short* __restrict__ Y0, unsigned short* __restrict__ Y1, int tot) {
    const int t = threadIdx.x, w = t >> 6, lane = t & 63;
    const int lrow = lane & 15, lk = lane >> 4;
    const int rs = w & 1, ng = w >> 1;
    const int col0 = ng * 32;

    short8 wf[2][K / 32];
    f32x4 bv[2];
#pragma unroll
    for (int p = 0; p < 2; ++p) {
        bv[p] = *(const f32x4*)(bias + col0 + p * 16 + lk * 4);
#pragma unroll
        for (int kt = 0; kt < K / 32; ++kt)
            wf[p][kt] = *(const short8*)(Wt + (col0 + p * 16 + lrow) * K + kt * 32 + lk * 8);
    }

    int T = blockIdx.x;
    if (T >= tot) return;

    auto loadx = [&](int TT, short8* xf) {
        const int half = TT >= NTILES;
        const void* A = half ? A1 : A0;
        const int row = (TT - half * NTILES) * 32 + rs * 16 + lrow;
        if constexpr (AF32) {
            const float* X = (const float*)A + (size_t)row * K;
#pragma unroll
            for (int kt = 0; kt < K / 32; ++kt) {
                f32x4 f0 = *(const f32x4*)(X + kt * 32 + lk * 8);
                f32x4 f1 = *(const f32x4*)(X + kt * 32 + lk * 8 + 4);
                short8 v;
#pragma unroll
                for (int e = 0; e < 4; ++e) { v[e] = (short)f2b(f0[e]); v[4 + e] = (short)f2b(f1[e]); }
                xf[kt] = v;
            }
        } else {
            const unsigned short* X = (const unsigned short*)A + (size_t)row * K;
#pragma unroll
            for (int kt = 0; kt < K / 32; ++kt)
                xf[kt] = *(const short8*)(X + kt * 32 + lk * 8);
        }
    };

    short8 xf[K / 32], xn[K / 32];
    loadx(T, xf);
    for (;;) {
        const int Tn = T + gridDim.x;
        const bool more = Tn < tot;
        if (more) loadx(Tn, xn);

        const int half = T >= NTILES;
        unsigned short* Y = half ? Y1 : Y0;
        const int row = (T - half * NTILES) * 32 + rs * 16 + lrow;
#pragma unroll
        for (int p = 0; p < 2; ++p) {
            f32x4 acc = {0.f, 0.f, 0.f, 0.f};
#pragma unroll
            for (int kt = 0; kt < K / 32; ++kt)
                acc = __builtin_amdgcn_mfma_f32_16x16x32_bf16(wf[p][kt], xf[kt], acc, 0, 0, 0);
            float v0 = acc[0] + bv[p][0]; v0 = v0 > 0.f ? v0 : 0.f;
            float v1 = acc[1] + bv[p][1]; v1 = v1 > 0.f ? v1 : 0.f;
            float v2 = acc[2] + bv[p][2]; v2 = v2 > 0.f ? v2 : 0.f;
            float v3 = acc[3] + bv[p][3]; v3 = v3 > 0.f ? v3 : 0.f;
            u32x2 ov = {(unsigned)f2b(v0) | ((unsigned)f2b(v1) << 16),
                        (unsigned)f2b(v2) | ((unsigned)f2b(v3) << 16)};
            *(u32x2*)(Y + (size_t)row * HID + col0 + p * 16 + lk * 4) = ov;
        }
        if (!more) break;
#pragma unroll
        for (int kt = 0; kt < K / 32; ++kt) xf[kt] = xn[kt];
        T = Tn;
    }
}

// Stage A: gather + aggregate. 32 rows/block, 16 thr/row x 4 cols (8B).
// Col-half split keeps each XCD's working set 2x1.28 MB (L2-resident).
// grid bid = ((h*ANCH + c) << 3) | b.  16 outstanding 8B loads per pass.
__global__ __launch_bounds__(512) void aggr3(
    const unsigned short* __restrict__ SE, const unsigned short* __restrict__ IE,
    const int* __restrict__ sidx, const int* __restrict__ iidx,
    unsigned short* __restrict__ G) {
    __shared__ int sh[32][33];            // padded
    const int t = threadIdx.x;
    const int b = blockIdx.x & 7;
    const int hc = blockIdx.x >> 3;
    const int h = hc >= ANCH ? 1 : 0;
    const int c = hc - h * ANCH;
    const int n0 = c * 32;

#pragma unroll
    for (int q = 0; q < 2; ++q) {
        const int e = t + q * 512;        // < 1024
        const int r = e >> 5, k = e & 31;
        int nr = n0 + r; if (nr > NNODE - 1) nr = NNODE - 1;
        sh[r][k] = (k < KN) ? sidx[nr * KN + k] : iidx[nr * KN + (k - KN)];
    }
    __syncthreads();

    const int r = t >> 4, p = t & 15;
    const int col0 = h * 64 + p * 4;
    const int n = n0 + r;
    const size_t base = (size_t)b * NNODE * HID + col0;

    u32x2 vs[16], vi[16];
#pragma unroll
    for (int j = 0; j < 16; ++j)
        vs[j] = *(const u32x2*)(SE + base + (size_t)sh[r][j] * HID);
#pragma unroll
    for (int j = 0; j < 16; ++j)
        vi[j] = *(const u32x2*)(IE + base + (size_t)sh[r][16 + j] * HID);

    f32x2 a0 = {0.f, 0.f}, a1 = {0.f, 0.f};
#pragma unroll
    for (int j = 0; j < 16; ++j) {
        unsigned u0 = vs[j][0], u1 = vs[j][1];
        a0 += (f32x2){__uint_as_float(u0 << 16), __uint_as_float(u0 & 0xffff0000u)};
        a1 += (f32x2){__uint_as_float(u1 << 16), __uint_as_float(u1 & 0xffff0000u)};
    }
#pragma unroll
    for (int j = 0; j < 16; ++j) {
        unsigned u0 = vi[j][0], u1 = vi[j][1];
        a0 += (f32x2){__uint_as_float(u0 << 16), __uint_as_float(u0 & 0xffff0000u)};
        a1 += (f32x2){__uint_as_float(u1 << 16), __uint_as_float(u1 & 0xffff0000u)};
    }

    if (n < NNODE) {
        u32x2 ov = {(unsigned)f2b(a0.x) | ((unsigned)f2b(a0.y) << 16),
                    (unsigned)f2b(a1.x) | ((unsigned)f2b(a1.y) << 16)};
        *(u32x2*)(G + ((size_t)b * NNODE + n) * HID + col0) = ov;
    }
}

// Stage B: Y = relu([G|H] @ Wut^T + bu), transposed-operand, persistent W.
__global__ __launch_bounds__(512) void update_gemm2(
    const unsigned short* __restrict__ G, const unsigned short* __restrict__ H,
    const unsigned short* __restrict__ Wut, const float* __restrict__ bu,
    float* __restrict__ Yf, unsigned short* __restrict__ Yb, int writeb) {
    const int t = threadIdx.x, w = t >> 6, lane = t & 63;
    const int lrow = lane & 15, lk = lane >> 4;
    const int rs = w & 1, ng = w >> 1;
    const int col0 = ng * 32;

    short8 wf[2][8];
    f32x4 bv[2];
#pragma unroll
    for (int p = 0; p < 2; ++p) {
        bv[p] = *(const f32x4*)(bu + col0 + p * 16 + lk * 4);
#pragma unroll
        for (int kt = 0; kt < 8; ++kt)
            wf[p][kt] = *(const short8*)(Wut + (col0 + p * 16 + lrow) * 256 + kt * 32 + lk * 8);
    }

    for (int T = blockIdx.x; T < NTILES; T += gridDim.x) {
        const int row = T * 32 + rs * 16 + lrow;
        short8 xf[8];
#pragma unroll
        for (int kt = 0; kt < 4; ++kt) {
            xf[kt]     = *(const short8*)(G + (size_t)row * HID + kt * 32 + lk * 8);
            xf[4 + kt] = *(const short8*)(H + (size_t)row * HID + kt * 32 + lk * 8);
        }
#pragma unroll
        for (int p = 0; p < 2; ++p) {
            f32x4 acc = {0.f, 0.f, 0.f, 0.f};
#pragma unroll
            for (int kt = 0; kt < 8; ++kt)
                acc = __builtin_amdgcn_mfma_f32_16x16x32_bf16(wf[p][kt], xf[kt], acc, 0, 0, 0);
            f32x4 o;
#pragma unroll
            for (int j = 0; j < 4; ++j) {
                float v = acc[j] + bv[p][j];
                o[j] = v > 0.f ? v : 0.f;
            }
            *(f32x4*)(Yf + (size_t)row * HID + col0 + p * 16 + lk * 4) = o;
            if (writeb) {
                u32x2 ov = {(unsigned)f2b(o[0]) | ((unsigned)f2b(o[1]) << 16),
                            (unsigned)f2b(o[2]) | ((unsigned)f2b(o[3]) << 16)};
                *(u32x2*)(Yb + (size_t)row * HID + col0 + p * 16 + lk * 4) = ov;
            }
        }
    }
}

extern "C" void kernel_launch(void* const* d_in, const int* in_sizes, int n_in,
                              void* d_out, int out_size, void* d_ws, size_t ws_size,
                              hipStream_t stream) {
    const float* state    = (const float*)d_in[0];
    const float* internal = (const float*)d_in[1];
    const int*   sidx     = (const int*)d_in[2];
    const int*   iidx     = (const int*)d_in[3];
    const float* W1  = (const float*)d_in[4];
    const float* b1  = (const float*)d_in[5];
    const float* W2  = (const float*)d_in[6];
    const float* b2  = (const float*)d_in[7];
    const float* Wu1 = (const float*)d_in[8];
    const float* bu1 = (const float*)d_in[9];
    const float* Wu2 = (const float*)d_in[10];
    const float* bu2 = (const float*)d_in[11];

    float* hu1 = (float*)d_out;
    float* hu2 = hu1 + (size_t)ROWS * HID;

    unsigned short* W1t  = (unsigned short*)d_ws;          // [128][64]
    unsigned short* W2t  = W1t  + 64 * 128;                // [128][128]
    unsigned short* Wu1t = W2t  + 128 * 128;               // [128][256]
    unsigned short* Wu2t = Wu1t + 256 * 128;               // [128][256]
    unsigned short* bufA = Wu2t + 256 * 128;               // [ROWS][128] bf16 each
    unsigned short* bufB = bufA + (size_t)ROWS * HID;
    unsigned short* bufC = bufB + (size_t)ROWS * HID;
    unsigned short* bufD = bufC + (size_t)ROWS * HID;

    const size_t need4 = (size_t)90112 * 2 + 4 * (size_t)ROWS * HID * 2;
    const bool big = ws_size >= need4;

    dim3 b256(256), b512(512);
    const int AGRID = 8 * 2 * ANCH;   // 5008

    wconv_all<<<352, b256, 0, stream>>>(W1, W2, Wu1, Wu2, W1t, W2t, Wu1t, Wu2t);

    // layer-1 embeddings: SE1 -> bufA, IE1 -> bufB (one launch, 5000 tiles)
    embed2<64, true><<<1250, b512, 0, stream>>>(state, internal, W1t, b1, bufA, bufB, 2 * NTILES);

    if (big) {
        // aggr1 -> bufD; hu1 = relu([aggr1|IE1]@Wu1+bu1) -> d_out + bufC
        aggr3<<<AGRID, b512, 0, stream>>>(bufA, bufB, sidx, iidx, bufD);
        update_gemm2<<<1250, b512, 0, stream>>>(bufD, bufB, Wu1t, bu1, hu1, bufC, 1);
        // se2: bufA -> bufB; ie2: bufC -> bufD (one launch, disjoint)
        embed2<128, false><<<1250, b512, 0, stream>>>(bufA, bufC, W2t, b2, bufB, bufD, 2 * NTILES);
        // aggr2 -> bufA; hu2 = relu([aggr2|ie2]@Wu2+bu2) -> d_out
        aggr3<<<AGRID, b512, 0, stream>>>(bufB, bufD, sidx, iidx, bufA);
        update_gemm2<<<1250, b512, 0, stream>>>(bufA, bufD, Wu2t, bu2, hu2, nullptr, 0);
    } else {
        // 3-buffer fallback: use the hu2 region (written last) as bf16 scratch.
        unsigned short* Ghu2 = (unsigned short*)hu2;
        aggr3<<<AGRID, b512, 0, stream>>>(bufA, bufB, sidx, iidx, Ghu2);
        update_gemm2<<<1250, b512, 0, stream>>>(Ghu2, bufB, Wu1t, bu1, hu1, bufC, 1);
        embed2<128, false><<<1250, b512, 0, stream>>>(bufA, nullptr, W2t, b2, bufB, nullptr, NTILES);
        embed2<128, false><<<1250, b512, 0, stream>>>(bufC, nullptr, W2t, b2, bufA, nullptr, NTILES);
        aggr3<<<AGRID, b512, 0, stream>>>(bufB, bufA, sidx, iidx, bufC);
        update_gemm2<<<1250, b512, 0, stream>>>(bufC, bufA, Wu2t, bu2, hu2, nullptr, 0);
    }
}